// Round 7
// baseline (244.620 us; speedup 1.0000x reference)
//
#include <hip/hip_runtime.h>
#include <hip/hip_bf16.h>
#include <math.h>

#define NWRD 2000
#define BB 64
#define CS 128
#define VV 256

typedef __attribute__((ext_vector_type(8)))  short short8;   // 8 bf16 (4 VGPRs)
typedef __attribute__((ext_vector_type(16))) float f32x16;   // MFMA 32x32 acc

// workspace layout (float offsets)
#define WS_FC2WT 0                         // 256*256 bf16
#define WS_WCODE (WS_FC2WT + 32768)        // 64*6000 f32  ([b][n])
#define WS_VSB   (WS_WCODE + 384000)       // 256*32 bf16
#define WS_VCB   (WS_VSB + 4096)           // 64*128*256 bf16
#define WS_FCEWT (WS_VCB + 1048576)        // 32*256 bf16
#define WS_FCAWB (WS_FCEWT + 4096)         // 32*256 bf16 (col0=fca_w, rest 0)

__device__ __forceinline__ unsigned short f2bf(float x) {
    unsigned int u = __float_as_uint(x);
    u += 0x7fffu + ((u >> 16) & 1u);       // round-to-nearest-even
    return (unsigned short)(u >> 16);
}

// ================ KPREP_LIGHT: independent small prep jobs ================
// [0,1024): vcb | [1024,1056): vsb | [1056,1072): fc2wT | 1072: fcewT+fcawB
#define PL_A 1024
#define PL_B (PL_A + 32)
#define PL_C (PL_B + 16)
#define PL_N (PL_C + 1)
__global__ __launch_bounds__(256) void kprep_light(
        const float* __restrict__ vc, unsigned short* __restrict__ vcb,
        const float* __restrict__ vse_w1, const float* __restrict__ vse_b1,
        const float* __restrict__ vse_w2, const float* __restrict__ vse_b2,
        unsigned short* __restrict__ vsb,
        const float* __restrict__ fc2_w, unsigned short* __restrict__ fc2wT,
        const float* __restrict__ fce_w, unsigned short* __restrict__ fcewT,
        const float* __restrict__ fca_w, unsigned short* __restrict__ fcawB) {
    __shared__ unsigned short smem[9216];
    int bid = blockIdx.x, t = threadIdx.x;
    if (bid < PL_A) {
        int i = (bid * 256 + t) * 8;
        float4 f0 = *(const float4*)(vc + i);
        float4 f1 = *(const float4*)(vc + i + 4);
        union { short8 v8; unsigned short u[8]; } o;
        o.u[0] = f2bf(f0.x); o.u[1] = f2bf(f0.y); o.u[2] = f2bf(f0.z); o.u[3] = f2bf(f0.w);
        o.u[4] = f2bf(f1.x); o.u[5] = f2bf(f1.y); o.u[6] = f2bf(f1.z); o.u[7] = f2bf(f1.w);
        *(short8*)(vcb + i) = o.v8;
    } else if (bid < PL_B) {
        float* hs = (float*)smem;   // [8][128]
        int blk = bid - PL_A;
        int m = t & 127, half = t >> 7;
#pragma unroll
        for (int q = 0; q < 4; q++) {
            int vloc = half*4 + q;
            int vv = blk*8 + vloc;
            float x = (2.f/15.f)*(float)(vv >> 4) - 1.f;
            float y = (2.f/15.f)*(float)(vv & 15) - 1.f;
            float h = vse_b1[m] + x*vse_w1[m] + y*vse_w1[128 + m];
            hs[vloc*128 + m] = fmaxf(h, 0.f);
        }
        __syncthreads();
        int vloc = t >> 5, e = t & 31;
        float s = vse_b2[e];
        for (int mm = 0; mm < 128; mm++) s = fmaf(hs[vloc*128 + mm], vse_w2[mm*32 + e], s);
        vsb[(blk*8 + vloc)*32 + e] = f2bf(s);
    } else if (bid < PL_C) {
        unsigned short (*tile)[72] = (unsigned short(*)[72])smem;
        int b2 = bid - PL_B;
        int k0t = (b2 >> 2) * 64, n0t = (b2 & 3) * 64;
        int nl = t & 63, kb = (t >> 6) * 16;
#pragma unroll
        for (int i = 0; i < 16; i++)
            tile[kb + i][nl] = f2bf(fc2_w[(size_t)(k0t + kb + i)*256 + n0t + nl]);
        __syncthreads();
        int kl = t & 63, nb = (t >> 6) * 16;
#pragma unroll
        for (int i = 0; i < 16; i++)
            fc2wT[(size_t)(n0t + nb + i)*256 + k0t + kl] = tile[kl][nb + i];
    } else {
        int e = t & 31, kb = (t >> 5) * 32;
        unsigned short tmp[32];
#pragma unroll
        for (int i = 0; i < 32; i++) tmp[i] = f2bf(fce_w[(size_t)(kb + i)*32 + e]);
#pragma unroll
        for (int i = 0; i < 4; i++)
            *(short8*)(fcewT + (size_t)e*256 + kb + i*8) = *(short8*)(tmp + i*8);
#pragma unroll
        for (int i = 0; i < 32; i++)
            fcawB[(size_t)e*256 + kb + i] = (e == 0) ? f2bf(fca_w[kb + i]) : (unsigned short)0;
    }
}

// ================ KPREP_W2: w2 staged to LDS once + wcode MFMA ================
// 94 blocks x 256 thr. Block: 64 n-cols. LDS: h0L[64][520] + w2L[64][520] bf16.
#define W2_LDS (64*520*2*2)
__global__ __launch_bounds__(256) void kprep_w2(
        const float* __restrict__ w2, const float* __restrict__ v,
        const float* __restrict__ w2c_w1, const float* __restrict__ w2c_b1,
        const float* __restrict__ w2c_b2, float* __restrict__ wcode) {
    extern __shared__ char plds[];
    unsigned short* h0L = (unsigned short*)plds;             // [64][520]
    unsigned short* w2L = (unsigned short*)(plds + 64*520*2);// [64][520]
    int t = threadIdx.x;
    int n0 = blockIdx.x * 64;
    // ---- stage w2 columns (k-contiguous per n), coalesced reads, read-once
    {
        int nl = t & 63, kq = t >> 6;
        int ncl = (n0 + nl) < 6000 ? (n0 + nl) : 5999;
#pragma unroll 4
        for (int k = kq*128; k < kq*128 + 128; k += 2) {
            unsigned int p = (unsigned int)f2bf(w2[(size_t)k*6000 + ncl])
                           | ((unsigned int)f2bf(w2[(size_t)(k+1)*6000 + ncl]) << 16);
            *(unsigned int*)(w2L + nl*520 + k) = p;
        }
    }
    // ---- compute h0 locally (redundant per block, trivial): j-pair per thread
    {
        int j0 = t * 2;
        float wk0[7], wk1[7];
#pragma unroll
        for (int k = 0; k < 7; k++) { wk0[k] = w2c_w1[k*512 + j0]; wk1[k] = w2c_w1[k*512 + j0 + 1]; }
        float bb0 = w2c_b1[j0], bb1 = w2c_b1[j0 + 1];
        for (int b = 0; b < 64; b++) {
            float s0 = bb0, s1 = bb1;
#pragma unroll
            for (int k = 0; k < 7; k++) {
                float vv = v[b*7 + k];
                s0 = fmaf(vv, wk0[k], s0);
                s1 = fmaf(vv, wk1[k], s1);
            }
            unsigned int p = (unsigned int)f2bf(fmaxf(s0, 0.f))
                           | ((unsigned int)f2bf(fmaxf(s1, 0.f)) << 16);
            *(unsigned int*)(h0L + b*520 + j0) = p;
        }
    }
    __syncthreads();
    // ---- wcode tile (64 b x 64 n) via MFMA, K=512
    int w = t >> 6, lane = t & 63, l31 = lane & 31, h = lane >> 5;
    int mt = w & 1, nt = w >> 1;
    f32x16 acc;
#pragma unroll
    for (int i = 0; i < 16; i++) acc[i] = 0.f;
#pragma unroll 8
    for (int ks = 0; ks < 32; ks++) {
        int k0 = ks*16 + h*8;
        short8 af = *(const short8*)(h0L + (mt*32 + l31)*520 + k0);
        short8 bf = *(const short8*)(w2L + (nt*32 + l31)*520 + k0);
        acc = __builtin_amdgcn_mfma_f32_32x32x16_bf16(af, bf, acc, 0, 0, 0);
    }
    int n = n0 + nt*32 + l31;
    if (n < 6000) {
        float bias = w2c_b2[n];
#pragma unroll
        for (int i = 0; i < 16; i++) {
            int row = (i & 3) + 8*(i >> 2) + 4*h;
            wcode[(size_t)(mt*32 + row)*6000 + n] = acc[i] + bias;
        }
    }
}

// ================ K45: fused MLP + relation + softmax + einsum ================
// grid (8 nblk, 64 b), 512 threads (8 waves), 4 chunks of 64 words, 4 barriers.
// LDS: h1b[64][264] @0 | h2b/routeB[64][264] @33792 | embL[64][40] @67584 |
//      actL[64] @72704 | wcsAll[768] @72960 | redS[8][32] @76032. total 77056 B
#define K45_LDS 77056
__global__ __launch_bounds__(512, 4) void k45(
        const unsigned short* __restrict__ vcb,
        const float* __restrict__ wcode,
        const float* __restrict__ fc1_w, const float* __restrict__ fc1_b,
        const unsigned short* __restrict__ fc2wT, const float* __restrict__ fc2_b,
        const float* __restrict__ fca_b_p,
        const unsigned short* __restrict__ fcawB,
        const unsigned short* __restrict__ fcewT, const float* __restrict__ fce_b,
        const unsigned short* __restrict__ vsb,
        float* __restrict__ out) {
    extern __shared__ char lds[];
    unsigned short* h1b    = (unsigned short*)lds;            // [64][264]
    unsigned short* h2b    = (unsigned short*)(lds + 33792);  // [64][264]
    unsigned short* routeB = h2b;                             // alias (h2 dead by write time)
    unsigned short* embL   = (unsigned short*)(lds + 67584);  // [64][40]
    float* actL   = (float*)(lds + 72704);                    // [64]
    float* wcsAll = (float*)(lds + 72960);                    // [768]
    float* redS   = (float*)(lds + 76032);                    // [8][32]
    int t = threadIdx.x;
    int w = t >> 6, lane = t & 63, l31 = lane & 31, h = lane >> 5;
    int b = blockIdx.y;
    int n0 = blockIdx.x * 256;

    // ---- stage all 4 chunks' wcode once (768 f32)
    {
        const float* wb = wcode + (size_t)b*6000;
        int i0 = n0*3 + t;
        wcsAll[t] = wb[i0 < 6000 ? i0 : 5999];
        if (t < 256) {
            int i1 = n0*3 + 512 + t;
            wcsAll[512 + t] = wb[i1 < 6000 ? i1 : 5999];
        }
    }
    // hoisted invariants
    int jq = (t & 63) * 4;
    float4 wa  = *(const float4*)(fc1_w + jq);
    float4 wb4 = *(const float4*)(fc1_w + 256 + jq);
    float4 wc  = *(const float4*)(fc1_w + 512 + jq);
    float4 bb4 = *(const float4*)(fc1_b + jq);
    int mtA = w & 1, na = (w >> 1) * 32, nb2 = na + 128;      // fc2 tiling
    float ba = fc2_b[na + l31], bbv = fc2_b[nb2 + l31];
    float be = fce_b[l31];
    float fcab = fca_b_p[0];
    int ntR = w & 1, vq = w >> 1;                             // relation tiling
    int ctE = w >> 1, ntE = w & 1;                            // einsum tiling
    size_t arowE = ((size_t)(b*128 + ctE*32 + l31))*256;
    __syncthreads();

    for (int c = 0; c < 4; c++) {
        int w0 = n0 + c*64;
        // ---- fc1 (VALU) -> h1b   (overlaps prev chunk's einsum)
#pragma unroll
        for (int rr = 0; rr < 8; rr++) {
            int r = w*8 + rr;
            const float* wr = wcsAll + (c*64 + r)*3;
            float c0 = wr[0], c1 = wr[1], c2 = wr[2];
            float v0 = fmaxf(fmaf(c2, wc.x, fmaf(c1, wb4.x, fmaf(c0, wa.x, bb4.x))), 0.f);
            float v1 = fmaxf(fmaf(c2, wc.y, fmaf(c1, wb4.y, fmaf(c0, wa.y, bb4.y))), 0.f);
            float v2 = fmaxf(fmaf(c2, wc.z, fmaf(c1, wb4.z, fmaf(c0, wa.z, bb4.z))), 0.f);
            float v3 = fmaxf(fmaf(c2, wc.w, fmaf(c1, wb4.w, fmaf(c0, wa.w, bb4.w))), 0.f);
            uint2 p;
            p.x = (unsigned int)f2bf(v0) | ((unsigned int)f2bf(v1) << 16);
            p.y = (unsigned int)f2bf(v2) | ((unsigned int)f2bf(v3) << 16);
            *(uint2*)(h1b + r*264 + jq) = p;
        }
        __syncthreads();   // B1: h1b ready; prev einsum's routeB reads done
        // ---- fc2 (MFMA) -> h2b
        {
            f32x16 c0, c1;
#pragma unroll
            for (int i = 0; i < 16; i++) { c0[i] = 0.f; c1[i] = 0.f; }
#pragma unroll 4
            for (int ks = 0; ks < 16; ks++) {
                int k0 = ks*16 + h*8;
                short8 af  = *(const short8*)(h1b + (mtA*32 + l31)*264 + k0);
                short8 bfa = *(const short8*)(fc2wT + (size_t)(na  + l31)*256 + k0);
                short8 bfb = *(const short8*)(fc2wT + (size_t)(nb2 + l31)*256 + k0);
                c0 = __builtin_amdgcn_mfma_f32_32x32x16_bf16(af, bfa, c0, 0, 0, 0);
                c1 = __builtin_amdgcn_mfma_f32_32x32x16_bf16(af, bfb, c1, 0, 0, 0);
            }
#pragma unroll
            for (int i = 0; i < 16; i++) {
                int row = (i & 3) + 8*(i >> 2) + 4*h;
                h2b[(mtA*32 + row)*264 + na  + l31] = f2bf(fmaxf(c0[i] + ba, 0.f));
                h2b[(mtA*32 + row)*264 + nb2 + l31] = f2bf(fmaxf(c1[i] + bbv, 0.f));
            }
        }
        __syncthreads();   // B2
        // ---- fce (waves 0-1) + fca-as-MFMA (waves 2-3) -> embL, actL
        if (w < 2) {
            f32x16 ce;
#pragma unroll
            for (int i = 0; i < 16; i++) ce[i] = 0.f;
#pragma unroll 4
            for (int ks = 0; ks < 16; ks++) {
                int k0 = ks*16 + h*8;
                short8 af = *(const short8*)(h2b + (w*32 + l31)*264 + k0);
                short8 bf = *(const short8*)(fcewT + (size_t)l31*256 + k0);
                ce = __builtin_amdgcn_mfma_f32_32x32x16_bf16(af, bf, ce, 0, 0, 0);
            }
#pragma unroll
            for (int i = 0; i < 16; i++) {
                int row = (i & 3) + 8*(i >> 2) + 4*h;
                embL[(w*32 + row)*40 + l31] = f2bf(ce[i] + be);
            }
        } else if (w < 4) {
            int m = w - 2;
            f32x16 ca;
#pragma unroll
            for (int i = 0; i < 16; i++) ca[i] = 0.f;
#pragma unroll 4
            for (int ks = 0; ks < 16; ks++) {
                int k0 = ks*16 + h*8;
                short8 af = *(const short8*)(h2b + (m*32 + l31)*264 + k0);
                short8 bf = *(const short8*)(fcawB + (size_t)l31*256 + k0);
                ca = __builtin_amdgcn_mfma_f32_32x32x16_bf16(af, bf, ca, 0, 0, 0);
            }
            if (l31 == 0) {
#pragma unroll
                for (int i = 0; i < 16; i++) {
                    int row = (i & 3) + 8*(i >> 2) + 4*h;
                    actL[m*32 + row] = 1.f / (1.f + __expf(-(ca[i] + fcab)));
                }
            }
        }
        __syncthreads();   // B3: embL, actL ready
        // ---- relation (MFMA): wave = (n-tile ntR, v-quarter vq)
        int nloc = ntR*32 + l31;
        f32x16 ra[2];
#pragma unroll
        for (int mt = 0; mt < 2; mt++)
#pragma unroll
            for (int i = 0; i < 16; i++) ra[mt][i] = 0.f;
#pragma unroll
        for (int s = 0; s < 2; s++) {
            short8 bfrag = *(const short8*)(embL + nloc*40 + s*16 + h*8);
#pragma unroll
            for (int mt = 0; mt < 2; mt++) {
                int vrow = (vq*2 + mt)*32 + l31;
                short8 afrag = *(const short8*)(vsb + vrow*32 + s*16 + h*8);
                ra[mt] = __builtin_amdgcn_mfma_f32_32x32x16_bf16(afrag, bfrag, ra[mt], 0, 0, 0);
            }
        }
        // ---- exp (no max-sub: logits tiny) + partial sums -> redS; routeB unscaled
        float sm = 0.f;
#pragma unroll
        for (int mt = 0; mt < 2; mt++)
#pragma unroll
            for (int i = 0; i < 16; i++) {
                float e = __expf(ra[mt][i]);
                ra[mt][i] = e;
                sm += e;
            }
        sm += __shfl_xor(sm, 32);
        if (lane < 32) redS[w*32 + l31] = sm;
#pragma unroll
        for (int mt = 0; mt < 2; mt++) {
#pragma unroll
            for (int rp = 0; rp < 4; rp++) {
                int vb = (vq*2 + mt)*32 + rp*8 + h*4;
                unsigned int p0 = (unsigned int)f2bf(ra[mt][rp*4+0])
                                | ((unsigned int)f2bf(ra[mt][rp*4+1]) << 16);
                unsigned int p1 = (unsigned int)f2bf(ra[mt][rp*4+2])
                                | ((unsigned int)f2bf(ra[mt][rp*4+3]) << 16);
                *(uint2*)(routeB + nloc*264 + vb) = make_uint2(p0, p1);
            }
        }
        __syncthreads();   // B4: routeB + redS ready
        // ---- einsum (MFMA) + scale-in-epilogue: out[c][n] = (vcb @ routeB^T) * act/sum
        {
            f32x16 cc;
#pragma unroll
            for (int i = 0; i < 16; i++) cc[i] = 0.f;
            const unsigned short* rrow = routeB + (ntE*32 + l31)*264;
#pragma unroll 4
            for (int ks = 0; ks < 16; ks++) {
                int k0 = ks*16 + h*8;
                short8 bf = *(const short8*)(rrow + k0);
                short8 a0 = *(const short8*)(vcb + arowE + k0);
                cc = __builtin_amdgcn_mfma_f32_32x32x16_bf16(a0, bf, cc, 0, 0, 0);
            }
            float ssum = redS[ntE*32 + l31] + redS[(2 + ntE)*32 + l31]
                       + redS[(4 + ntE)*32 + l31] + redS[(6 + ntE)*32 + l31];
            float scl = actL[ntE*32 + l31] / ssum;
            int ng = w0 + ntE*32 + l31;
            if (ng < NWRD) {
                float* ob = out + (size_t)b*128*NWRD + ng;
#pragma unroll
                for (int i = 0; i < 16; i++) {
                    int crow = (i & 3) + 8*(i >> 2) + 4*h;
                    ob[(size_t)(ctE*32 + crow)*NWRD] = cc[i] * scl;
                }
            }
        }
        // no loop-top barrier: next fc1 writes h1b; B1 guards routeB reuse (h2b)
    }
}

extern "C" void kernel_launch(void* const* d_in, const int* in_sizes, int n_in,
                              void* d_out, int out_size, void* d_ws, size_t ws_size,
                              hipStream_t stream) {
    const float* view_cell = (const float*)d_in[0];
    const float* v       = (const float*)d_in[1];
    const float* w2c_w1  = (const float*)d_in[2];
    const float* w2c_b1  = (const float*)d_in[3];
    const float* w2c_w2  = (const float*)d_in[4];
    const float* w2c_b2  = (const float*)d_in[5];
    const float* fc1_w   = (const float*)d_in[6];
    const float* fc1_b   = (const float*)d_in[7];
    const float* fc2_w   = (const float*)d_in[8];
    const float* fc2_b   = (const float*)d_in[9];
    const float* fca_w   = (const float*)d_in[10];
    const float* fca_b   = (const float*)d_in[11];
    const float* fce_w   = (const float*)d_in[12];
    const float* fce_b   = (const float*)d_in[13];
    const float* vse_w1  = (const float*)d_in[14];
    const float* vse_b1  = (const float*)d_in[15];
    const float* vse_w2  = (const float*)d_in[16];
    const float* vse_b2  = (const float*)d_in[17];
    float* ws    = (float*)d_ws;
    unsigned short* fc2wT = (unsigned short*)(ws + WS_FC2WT);
    float* wcode = ws + WS_WCODE;
    unsigned short* vsb   = (unsigned short*)(ws + WS_VSB);
    unsigned short* vcb   = (unsigned short*)(ws + WS_VCB);
    unsigned short* fcewT = (unsigned short*)(ws + WS_FCEWT);
    unsigned short* fcawB = (unsigned short*)(ws + WS_FCAWB);
    float* out   = (float*)d_out;

    kprep_light<<<PL_N, 256, 0, stream>>>(view_cell, vcb,
                                          vse_w1, vse_b1, vse_w2, vse_b2, vsb,
                                          fc2_w, fc2wT, fce_w, fcewT, fca_w, fcawB);
    (void)hipFuncSetAttribute((const void*)kprep_w2,
                              hipFuncAttributeMaxDynamicSharedMemorySize, W2_LDS);
    kprep_w2<<<94, 256, W2_LDS, stream>>>(w2c_w2, v, w2c_w1, w2c_b1, w2c_b2, wcode);
    (void)hipFuncSetAttribute((const void*)k45,
                              hipFuncAttributeMaxDynamicSharedMemorySize, K45_LDS);
    dim3 g45(8, 64);
    k45<<<g45, 512, K45_LDS, stream>>>(vcb, wcode, fc1_w, fc1_b, fc2wT, fc2_b,
                                       fca_b, fcawB, fcewT, fce_b, vsb, out);
}